// Round 8
// baseline (177.764 us; speedup 1.0000x reference)
//
#include <hip/hip_runtime.h>
#include <stdint.h>

#define DIMC 256
#define RTOT 1024
#define NE 64
#define NSLOT 1024
#define RCN 8      // r-chunks (grid.x)
#define RCW 128    // r-columns per chunk
#define TILE 32    // max slots per pass (2 MFMA m-tiles)
#define XSTR 264   // padded LDS row stride (bf16 elems); 528B keeps b128 reads spread
#define NTILE 16   // 8 L1 tiles (32kx128n) + 8 L2 tiles (16kx256n)

typedef short bfrag __attribute__((ext_vector_type(8)));
typedef float f32x4 __attribute__((ext_vector_type(4)));
typedef const __attribute__((address_space(1))) void* gptr_t;
typedef __attribute__((address_space(3))) void* lptr_t;

// ---------------- bucket slots by expert ----------------
__global__ __launch_bounds__(1024) void bucket_kernel(
    const int* __restrict__ idx, int* __restrict__ count,
    int* __restrict__ start, int* __restrict__ list) {
  __shared__ int cnt[NE];
  __shared__ int offs[NE];
  __shared__ int cur[NE];
  int t = threadIdx.x;
  if (t < NE) cnt[t] = 0;
  __syncthreads();
  int e = idx[t] & (NE - 1);
  atomicAdd(&cnt[e], 1);
  __syncthreads();
  if (t == 0) {
    int acc = 0;
    for (int i = 0; i < NE; ++i) { offs[i] = acc; cur[i] = acc; acc += cnt[i]; }
  }
  __syncthreads();
  if (t < NE) { count[t] = cnt[t]; start[t] = offs[t]; }
  int pos = atomicAdd(&cur[e], 1);
  list[pos] = t;
}

static __device__ __forceinline__ unsigned short f2bf(float f) {
  unsigned u = __float_as_uint(f);  // RNE
  return (unsigned short)((u + 0x7FFFu + ((u >> 16) & 1u)) >> 16);
}

static __device__ __forceinline__ bfrag pack8(const float* f) {
  union { unsigned short u[8]; bfrag v; } r;
#pragma unroll
  for (int i = 0; i < 8; ++i) r.u[i] = f2bf(f[i]);
  return r.v;
}

// Queue one 16 KB tile global->LDS via async DMA (width 16, fire-and-forget).
// LDS dest is wave-uniform base + lane*16B (hardware scatter); src is per-lane.
// row_shift/col_mask: 7/127 for 128-col tiles, 8/255 for 256-col tiles.
static __device__ __forceinline__ void dma_tile(
    const float* __restrict__ src, int row_stride, int row_shift, int col_mask,
    float* slot, int w, int l) {
#pragma unroll
  for (int i = 0; i < 2; ++i) {
    const int base = (i * 8 + w) * 256;   // float offset of this wave-chunk
    const int f = base + l * 4;           // this lane's float offset
    const int row = f >> row_shift;
    const int col = f & col_mask;
    __builtin_amdgcn_global_load_lds(
        (gptr_t)(src + (size_t)row * row_stride + col),
        (lptr_t)(slot + base), 16, 0, 0);
  }
}

// ---------------- fused 2-layer expert MLP via MFMA + DMA-staged weights ----
// grid: (8 r-chunks, 64 experts), 512 threads = 8 waves, 2 blocks/CU.
// Weights stream global->LDS exactly once per block (disjoint chunks across
// blocks -> compulsory device traffic). MFMA consumes from LDS only: no
// per-wave global-load latency chains, no VGPR prefetch arrays.
// Fragment maps (verified R6/R7): A[m=ln][k=kg*8+j], B[k=kg*8+j][n=ln],
// C/D col=ln, row=kg*4+reg.
__global__ __launch_bounds__(512) void mlp_kernel(
    const float* __restrict__ slots, const float* __restrict__ w1,
    const float* __restrict__ b1, const float* __restrict__ w2,
    const float* __restrict__ b2, const int* __restrict__ count,
    const int* __restrict__ start, const int* __restrict__ list,
    float* __restrict__ out) {
  const int rc = blockIdx.x;   // 0..7
  const int e  = blockIdx.y;   // 0..63
  const int n  = count[e];
  if (n == 0) return;
  const int t  = threadIdx.x;
  const int l  = t & 63;       // lane
  const int w  = t >> 6;       // wave 0..7
  const int ln = l & 15;       // fragment n/m index
  const int kg = l >> 4;       // k-group 0..3
  const int rbase = rc * RCW;
  const int st = start[e];

  __shared__ float wbuf[3][4096];            // ring of 16 KB weight tiles
  __shared__ unsigned short X[TILE * XSTR];  // bf16 A: x (L1), h (L2)
  __shared__ int sid[TILE];

  const float* w1e = w1 + (size_t)e * DIMC * RTOT + rbase;                // [d][r]
  const float* w2e = w2 + (size_t)e * RTOT * DIMC + (size_t)rbase * DIMC; // [r][dout]

  for (int s0 = 0; s0 < n; s0 += TILE) {
    const int m = (n - s0 < TILE) ? (n - s0) : TILE;

    __syncthreads();
    if (t < TILE) sid[t] = (t < m) ? list[st + s0 + t] : 0;
    __syncthreads();

    // queue DMA for tile 0 while staging the x tile
    dma_tile(w1e, RTOT, 7, 127, wbuf[0], w, l);
    for (int i = t; i < TILE * 64; i += 512) {
      int s = i >> 6, d4 = (i & 63) * 4;
      float4 v = make_float4(0.f, 0.f, 0.f, 0.f);
      if (s < m) v = ((const float4*)slots)[(size_t)sid[s] * 64 + (i & 63)];
      union { unsigned short u[4]; uint2 q; } p;
      p.u[0] = f2bf(v.x); p.u[1] = f2bf(v.y);
      p.u[2] = f2bf(v.z); p.u[3] = f2bf(v.w);
      *(uint2*)&X[s * XSTR + d4] = p.q;
    }
    __syncthreads();  // x ready + tile 0 DMA drained

    f32x4 acc1[2];
    acc1[0] = (f32x4)(0.f); acc1[1] = (f32x4)(0.f);
    f32x4 acc2[2][2];

    for (int tk = 0; tk < NTILE; ++tk) {
      // queue next tile's DMA (overlaps this step's compute; end barrier drains)
      if (tk + 1 < NTILE) {
        const int kn = tk + 1;
        if (kn < 8)
          dma_tile(w1e + (size_t)(32 * kn) * RTOT, RTOT, 7, 127,
                   wbuf[kn % 3], w, l);
        else
          dma_tile(w2e + (size_t)(16 * (kn - 8)) * DIMC, DIMC, 8, 255,
                   wbuf[kn % 3], w, l);
      }

      if (tk < 8) {
        // ---- L1 step: K=32 rows of w1 chunk; wave owns 16 cols
        const float* B = wbuf[tk % 3];
        const int col = w * 16 + ln;
        float bv[8];
#pragma unroll
        for (int j = 0; j < 8; ++j) bv[j] = B[(kg * 8 + j) * 128 + col];
        bfrag b = pack8(bv);
        const unsigned short* xp = &X[(size_t)ln * XSTR + tk * 32 + kg * 8];
        bfrag a0 = *(const bfrag*)xp;
        bfrag a1 = *(const bfrag*)(xp + 16 * XSTR);
        acc1[0] = __builtin_amdgcn_mfma_f32_16x16x32_bf16(a0, b, acc1[0], 0, 0, 0);
        acc1[1] = __builtin_amdgcn_mfma_f32_16x16x32_bf16(a1, b, acc1[1], 0, 0, 0);

        if (tk == 7) {
          __syncthreads();  // all waves done reading x from X
          // bias + relu, park h (bf16) into X[m][r_local]
          const float b1v = b1[e * RTOT + rbase + col];
#pragma unroll
          for (int mt = 0; mt < 2; ++mt) {
#pragma unroll
            for (int reg = 0; reg < 4; ++reg) {
              float h = fmaxf(acc1[mt][reg] + b1v, 0.f);
              X[(mt * 16 + kg * 4 + reg) * XSTR + col] = f2bf(h);
            }
          }
#pragma unroll
          for (int mt = 0; mt < 2; ++mt)
#pragma unroll
            for (int nt = 0; nt < 2; ++nt) acc2[mt][nt] = (f32x4)(0.f);
        }
      } else if (tk & 1) {
        // ---- L2 step: K=32 from tile pair (tk-1, tk); wave owns 32 out cols
        const int ks2 = (tk - 9) >> 1;          // 0..3
        const float* Be = wbuf[(tk - 1) % 3];   // pair k 0..15
        const float* Bo = wbuf[tk % 3];         // pair k 16..31
        const float* Bk = (kg & 2) ? Bo : Be;
        const int krow = (kg & 1) * 8;
        const unsigned short* xp = &X[(size_t)ln * XSTR + ks2 * 32 + kg * 8];
        bfrag a0 = *(const bfrag*)xp;
        bfrag a1 = *(const bfrag*)(xp + 16 * XSTR);
#pragma unroll
        for (int nt = 0; nt < 2; ++nt) {
          const int col = w * 32 + nt * 16 + ln;
          float bv[8];
#pragma unroll
          for (int j = 0; j < 8; ++j) bv[j] = Bk[(krow + j) * 256 + col];
          bfrag b = pack8(bv);
          acc2[0][nt] = __builtin_amdgcn_mfma_f32_16x16x32_bf16(a0, b, acc2[0][nt], 0, 0, 0);
          acc2[1][nt] = __builtin_amdgcn_mfma_f32_16x16x32_bf16(a1, b, acc2[1][nt], 0, 0, 0);
        }
      }
      __syncthreads();  // tile consumed by all waves; next DMA drained
    }

    // ---- epilogue: out[sid[row]][col] += acc2 (+ b2 once via rc==0)
#pragma unroll
    for (int nt = 0; nt < 2; ++nt) {
      const int col = w * 32 + nt * 16 + ln;
      const float b2v = (rc == 0) ? b2[e * DIMC + col] : 0.f;
#pragma unroll
      for (int mt = 0; mt < 2; ++mt)
#pragma unroll
        for (int reg = 0; reg < 4; ++reg) {
          const int row = mt * 16 + kg * 4 + reg;
          if (row < m)
            atomicAdd(&out[(size_t)sid[row] * DIMC + col], acc2[mt][nt][reg] + b2v);
        }
    }

    // reset acc1 for a (rare) second pass
    acc1[0] = (f32x4)(0.f); acc1[1] = (f32x4)(0.f);
  }
}

extern "C" void kernel_launch(void* const* d_in, const int* in_sizes, int n_in,
                              void* d_out, int out_size, void* d_ws, size_t ws_size,
                              hipStream_t stream) {
  const float* slots   = (const float*)d_in[0];
  const float* w1      = (const float*)d_in[1];
  const float* b1      = (const float*)d_in[2];
  const float* w2      = (const float*)d_in[3];
  const float* b2      = (const float*)d_in[4];
  const int*   indices = (const int*)d_in[5];
  float* out = (float*)d_out;

  int* ws    = (int*)d_ws;
  int* count = ws;         // 64
  int* start = ws + 64;    // 64
  int* list  = ws + 128;   // 1024

  hipMemsetAsync(d_out, 0, (size_t)out_size * sizeof(float), stream);
  bucket_kernel<<<1, NSLOT, 0, stream>>>(indices, count, start, list);
  mlp_kernel<<<dim3(RCN, NE), 512, 0, stream>>>(slots, w1, b1, w2, b2,
                                                count, start, list, out);
}